// Round 3
// baseline (446.929 us; speedup 1.0000x reference)
//
#include <hip/hip_runtime.h>

#define N_TOK 2048
#define DIM   1024
#define NE    8
#define HID   2048
#define A_SHARED 4096
#define OUT_HID (N_TOK * DIM)

typedef float v4f __attribute__((ext_vector_type(4)));
typedef short v8s __attribute__((ext_vector_type(8)));

// ---- workspace layout (bytes) ----
// No bf16 weight copies anymore: GEMMs read f32 weights directly and
// convert during LDS staging.
#define OFF_XBF   0ull
#define OFF_H     4194304ull
#define OFF_TOK   29360128ull
#define OFF_WL    (OFF_TOK + 24576ull)
#define OFF_IDX   (OFF_WL + 24576ull)
#define OFF_TW    (OFF_IDX + 16384ull)
#define OFF_STATS (OFF_TW + 16384ull)

struct Stats {
  int counts[NE];
  int fill[NE];
  int offs[NE + 2];
  float z2;
  float psum[NE];
};

__device__ __forceinline__ unsigned short f2bf(float f) {
  union { float f; unsigned u; } v; v.f = f;
  unsigned r = v.u + 0x7FFFu + ((v.u >> 16) & 1u);
  return (unsigned short)(r >> 16);
}
__device__ __forceinline__ unsigned pack2bf(float a, float b) {
  return (unsigned)f2bf(a) | ((unsigned)f2bf(b) << 16);
}

// HW packed f32->bf16 (RNE), one instr per 2 values. No builtin on gfx950.
__device__ __forceinline__ unsigned cvt2bf(float a, float b) {
  unsigned r;
  asm("v_cvt_pk_bf16_f32 %0, %1, %2" : "=v"(r) : "v"(a), "v"(b));
  return r;
}
// Convert 8 f32 (two float4) -> 8 bf16, store as one ds_write_b128.
__device__ __forceinline__ void st8bf(unsigned short* p, float4 a, float4 b) {
  uint4 o;
  o.x = cvt2bf(a.x, a.y);
  o.y = cvt2bf(a.z, a.w);
  o.z = cvt2bf(b.x, b.y);
  o.w = cvt2bf(b.z, b.w);
  *(uint4*)p = o;
}

__device__ __forceinline__ void async_lds16(const void* g, void* l) {
  __builtin_amdgcn_global_load_lds(
      (const __attribute__((address_space(1))) void*)g,
      (__attribute__((address_space(3))) void*)l, 16, 0, 0);
}

// ---- router (also emits the bf16 copy of x; x is read here anyway) ----
__global__ __launch_bounds__(256) void router_kernel(
    const float* __restrict__ x, const float* __restrict__ rw, const float* __restrict__ rb,
    unsigned short* __restrict__ xbf,
    int* __restrict__ idxbuf, float* __restrict__ twbuf, Stats* __restrict__ st) {
  int lane = threadIdx.x & 63;
  int wv = threadIdx.x >> 6;
  int n = blockIdx.x * 4 + wv;

  float acc[NE];
#pragma unroll
  for (int e = 0; e < NE; ++e) acc[e] = 0.f;

  const float4* x4 = (const float4*)(x + (size_t)n * DIM);
  uint2* xb2 = (uint2*)xbf + (size_t)n * 256;
#pragma unroll
  for (int q = 0; q < 4; ++q) {
    float4 xv = x4[q * 64 + lane];
    uint2 xo;
    xo.x = pack2bf(xv.x, xv.y);
    xo.y = pack2bf(xv.z, xv.w);
    xb2[q * 64 + lane] = xo;
#pragma unroll
    for (int e = 0; e < NE; ++e) {
      const float4* w4 = (const float4*)(rw + (size_t)e * DIM);
      float4 wvv = w4[q * 64 + lane];
      acc[e] += xv.x * wvv.x + xv.y * wvv.y + xv.z * wvv.z + xv.w * wvv.w;
    }
  }
#pragma unroll
  for (int off = 32; off; off >>= 1) {
#pragma unroll
    for (int e = 0; e < NE; ++e) acc[e] += __shfl_xor(acc[e], off);
  }

  float mx = acc[0];
#pragma unroll
  for (int e = 1; e < NE; ++e) mx = fmaxf(mx, acc[e]);
  float pr[NE];
  float es = 0.f;
#pragma unroll
  for (int e = 0; e < NE; ++e) { pr[e] = __expf(acc[e] - mx); es += pr[e]; }
  float inv = 1.f / es;
#pragma unroll
  for (int e = 0; e < NE; ++e) pr[e] *= inv;
  float z = mx + __logf(es);

  float b0 = -1e30f; int i0 = 0;
#pragma unroll
  for (int e = 0; e < NE; ++e) {
    float bb = acc[e] + rb[e];
    if (bb > b0) { b0 = bb; i0 = e; }
  }
  float b1 = -1e30f; int i1 = 0;
#pragma unroll
  for (int e = 0; e < NE; ++e) {
    if (e == i0) continue;
    float bb = acc[e] + rb[e];
    if (bb > b1) { b1 = bb; i1 = e; }
  }
  float l0 = acc[i0], l1 = acc[i1];
  float m2 = fmaxf(l0, l1);
  float e0 = __expf(l0 - m2), e1 = __expf(l1 - m2);
  float den = 1.f / (e0 + e1);
  float w0 = e0 * den, w1 = e1 * den;

  __shared__ float redp[4][9];
  __shared__ int redc[4][8];
  if (lane == 0) {
    idxbuf[n * 2] = i0; idxbuf[n * 2 + 1] = i1;
    twbuf[n * 2] = w0;  twbuf[n * 2 + 1] = w1;
#pragma unroll
    for (int e = 0; e < NE; ++e) redp[wv][e] = pr[e];
    redp[wv][8] = z * z;
#pragma unroll
    for (int e = 0; e < NE; ++e) redc[wv][e] = (e == i0) + (e == i1);
  }
  __syncthreads();
  int t = threadIdx.x;
  if (t < 9) {
    float s = redp[0][t] + redp[1][t] + redp[2][t] + redp[3][t];
    if (t < 8) atomicAdd(&st->psum[t], s);
    else       atomicAdd(&st->z2, s);
  } else if (t >= 16 && t < 24) {
    int e = t - 16;
    atomicAdd(&st->counts[e], redc[0][e] + redc[1][e] + redc[2][e] + redc[3][e]);
  }
}

// ---- scan ----
__global__ void scan_kernel(Stats* __restrict__ st, float* __restrict__ out) {
  if (threadIdx.x == 0 && blockIdx.x == 0) {
    int o = 0;
#pragma unroll
    for (int e = 0; e < NE; ++e) { st->offs[e] = o; o += st->counts[e]; }
    st->offs[NE] = o;
    st->offs[NE + 1] = o + N_TOK;
    float zl = st->z2 / (float)N_TOK * 1e-4f;
    float lb = 0.f;
#pragma unroll
    for (int e = 0; e < NE; ++e)
      lb += (st->psum[e] / (float)N_TOK) * ((float)st->counts[e] / (float)N_TOK);
    lb *= (float)NE;
    out[OUT_HID + 0] = 0.f;
    out[OUT_HID + 1] = zl;
    out[OUT_HID + 2] = lb;
  }
}

// ---- scatter ----
__global__ __launch_bounds__(256) void scatter_kernel(
    const int* __restrict__ idxbuf, const float* __restrict__ twbuf,
    Stats* __restrict__ st, int* __restrict__ tok, float* __restrict__ wl) {
  int n = blockIdx.x * 256 + threadIdx.x;
#pragma unroll
  for (int k = 0; k < 2; ++k) {
    int e = idxbuf[n * 2 + k];
    int pos = st->offs[e] + atomicAdd(&st->fill[e], 1);
    tok[pos] = n;
    wl[pos] = twbuf[n * 2 + k];
  }
  tok[A_SHARED + n] = n;
  wl[A_SHARED + n] = 1.f;
}

// ============================================================
// LDS swizzle (per 128x32 bf16 tile): 64 super-rows of 128 B
// (8 granules of 16 B); granule g of super-row R holds
// super-chunk g^(R&7). Fragment ds_read_b128s hit all 8
// bank-groups, 2 lanes each (free). Verified: 0 conflicts (r3).
//
// B-staging is reg-staged from the f32 weights (no cast
// kernel): per thread 2x float4 load -> v_cvt_pk_bf16_f32 ->
// one ds_write_b128 to the SAME LDS address async_lds16 used
// (base (w*2+q)*1024B + lane*16B), so the fragment-read side
// (lofs) is unchanged.  Loads for tile t+1 issue before the
// MFMA phase; cvt+ds_write land after it (issue-early/
// write-late), hiding HBM latency under MFMA.
//
// Grid note: blockIdx.x = n-tile (dense), blockIdx.y = m-tile
// (sparse). See r2/r3 note on XCD spread.
// ============================================================

// ---- gate+up grouped GEMM, 128x128 tile, double-buffered ----
__global__ __launch_bounds__(256, 2) void gateup_kernel(
    const float* __restrict__ gw, const float* __restrict__ uw,
    const float* __restrict__ shg, const float* __restrict__ shu,
    const unsigned short* __restrict__ xbf, const int* __restrict__ tok,
    const Stats* __restrict__ st, unsigned short* __restrict__ hbuf) {
  int e = blockIdx.z;
  int seg0 = st->offs[e];
  int cnt = st->offs[e + 1] - seg0;
  int m0 = blockIdx.y * 128;          // m-tile on Y (sparse)
  if (m0 >= cnt) return;
  int n0 = blockIdx.x * 128;          // n-tile on X (dense)

  __shared__ alignas(16) unsigned short As[2][128 * 32];
  __shared__ alignas(16) unsigned short Bg[2][128 * 32];
  __shared__ alignas(16) unsigned short Bu[2][128 * 32];

  int tid = threadIdx.x, l = tid & 63, w = tid >> 6;
  int wr = w >> 1, wc = w & 1;

  int sj = l >> 3;
  int ss = (l & 7) ^ sj;
  int grow = 2 * sj + (ss >> 2);
  int gch = ss & 3;

  const float* gbase = (e < NE) ? gw + (size_t)e * HID * DIM : shg;
  const float* ubase = (e < NE) ? uw + (size_t)e * HID * DIM : shu;

  const unsigned short* ap[2];
  const float* gp[2];
  const float* up[2];
#pragma unroll
  for (int q = 0; q < 2; ++q) {
    int row = (w * 2 + q) * 16 + grow;
    int ar = m0 + row; if (ar > cnt - 1) ar = cnt - 1;
    ap[q] = xbf + (size_t)tok[seg0 + ar] * DIM + gch * 8;
    size_t wb = (size_t)(n0 + row) * DIM + gch * 8;
    gp[q] = gbase + wb;
    up[q] = ubase + wb;
  }

  int lh = (l & 15) >> 1;
  int lofs = lh * 64 + ((((l & 1) * 4 + (l >> 4)) ^ lh) * 8);

  v4f accg[4][4], accu[4][4];
#pragma unroll
  for (int mi = 0; mi < 4; ++mi)
#pragma unroll
    for (int ni = 0; ni < 4; ++ni) {
      accg[mi][ni] = (v4f){0.f, 0.f, 0.f, 0.f};
      accu[mi][ni] = (v4f){0.f, 0.f, 0.f, 0.f};
    }

  float4 rg[2][2], ru[2][2];
  // prologue: tile 0 — B via regs, A via async
#pragma unroll
  for (int q = 0; q < 2; ++q) {
    rg[q][0] = ((const float4*)gp[q])[0];
    rg[q][1] = ((const float4*)gp[q])[1];
    ru[q][0] = ((const float4*)up[q])[0];
    ru[q][1] = ((const float4*)up[q])[1];
  }
#pragma unroll
  for (int q = 0; q < 2; ++q)
    async_lds16(ap[q], &As[0][(w * 2 + q) * 512]);
#pragma unroll
  for (int q = 0; q < 2; ++q) {
    st8bf(&Bg[0][(w * 2 + q) * 512 + l * 8], rg[q][0], rg[q][1]);
    st8bf(&Bu[0][(w * 2 + q) * 512 + l * 8], ru[q][0], ru[q][1]);
  }

  int pb = 0;
  for (int k0 = 0; k0 < DIM; k0 += 32, pb ^= 1) {
    __syncthreads();

    // read this iteration's fragments first...
    v8s af[4], bgf[4], buf_[4];
#pragma unroll
    for (int mi = 0; mi < 4; ++mi)
      af[mi] = *(const v8s*)&As[pb][(wr * 32 + mi * 8) * 64 + lofs];
#pragma unroll
    for (int ni = 0; ni < 4; ++ni) {
      bgf[ni]  = *(const v8s*)&Bg[pb][(wc * 32 + ni * 8) * 64 + lofs];
      buf_[ni] = *(const v8s*)&Bu[pb][(wc * 32 + ni * 8) * 64 + lofs];
    }

    int nb = pb ^ 1;
    int kn = k0 + 32;
    if (kn < DIM) {
      // issue next-tile loads now; they fly during the MFMA phase
#pragma unroll
      for (int q = 0; q < 2; ++q) {
        rg[q][0] = ((const float4*)(gp[q] + kn))[0];
        rg[q][1] = ((const float4*)(gp[q] + kn))[1];
        ru[q][0] = ((const float4*)(up[q] + kn))[0];
        ru[q][1] = ((const float4*)(up[q] + kn))[1];
      }
#pragma unroll
      for (int q = 0; q < 2; ++q)
        async_lds16(ap[q] + kn, &As[nb][(w * 2 + q) * 512]);
    }

#pragma unroll
    for (int mi = 0; mi < 4; ++mi)
#pragma unroll
      for (int ni = 0; ni < 4; ++ni) {
        accg[mi][ni] = __builtin_amdgcn_mfma_f32_16x16x32_bf16(af[mi], bgf[ni], accg[mi][ni], 0, 0, 0);
        accu[mi][ni] = __builtin_amdgcn_mfma_f32_16x16x32_bf16(af[mi], buf_[ni], accu[mi][ni], 0, 0, 0);
      }

    if (kn < DIM) {
#pragma unroll
      for (int q = 0; q < 2; ++q) {
        st8bf(&Bg[nb][(w * 2 + q) * 512 + l * 8], rg[q][0], rg[q][1]);
        st8bf(&Bu[nb][(w * 2 + q) * 512 + l * 8], ru[q][0], ru[q][1]);
      }
    }
  }

  int col = l & 15, rq = (l >> 4) * 4;
#pragma unroll
  for (int mi = 0; mi < 4; ++mi) {
#pragma unroll
    for (int rr = 0; rr < 4; ++rr) {
      int rl = wr * 64 + mi * 16 + rq + rr;
      if (m0 + rl < cnt) {
        size_t rowb = (size_t)(seg0 + m0 + rl) * HID + n0 + wc * 64;
#pragma unroll
        for (int ni = 0; ni < 4; ++ni) {
          float g = accg[mi][ni][rr], u = accu[mi][ni][rr];
          hbuf[rowb + ni * 16 + col] = f2bf(g * u / (1.f + __expf(-g)));
        }
      }
    }
  }
}

// ---- down grouped GEMM, 128x128 tile, double-buffered ----
__global__ __launch_bounds__(256, 2) void down_kernel(
    const float* __restrict__ dw, const float* __restrict__ shd,
    const unsigned short* __restrict__ hbuf,
    const int* __restrict__ tok, const float* __restrict__ wl,
    const Stats* __restrict__ st, float* __restrict__ out) {
  int e = blockIdx.z;
  int seg0 = st->offs[e];
  int cnt = st->offs[e + 1] - seg0;
  int m0 = blockIdx.y * 128;          // m-tile on Y (sparse)
  if (m0 >= cnt) return;
  int n0 = blockIdx.x * 128;          // n-tile on X (dense, over DIM)

  __shared__ alignas(16) unsigned short As[2][128 * 32];
  __shared__ alignas(16) unsigned short Bs[2][128 * 32];

  int tid = threadIdx.x, l = tid & 63, w = tid >> 6;
  int wr = w >> 1, wc = w & 1;

  int sj = l >> 3;
  int ss = (l & 7) ^ sj;
  int grow = 2 * sj + (ss >> 2);
  int gch = ss & 3;

  const float* dbase = (e < NE) ? dw + (size_t)e * DIM * HID : shd;

  const unsigned short* ap[2];
  const float* bp[2];
#pragma unroll
  for (int q = 0; q < 2; ++q) {
    int row = (w * 2 + q) * 16 + grow;
    int ar = m0 + row; if (ar > cnt - 1) ar = cnt - 1;
    ap[q] = hbuf + (size_t)(seg0 + ar) * HID + gch * 8;
    bp[q] = dbase + (size_t)(n0 + row) * HID + gch * 8;
  }

  int lh = (l & 15) >> 1;
  int lofs = lh * 64 + ((((l & 1) * 4 + (l >> 4)) ^ lh) * 8);

  v4f acc[4][4];
#pragma unroll
  for (int mi = 0; mi < 4; ++mi)
#pragma unroll
    for (int ni = 0; ni < 4; ++ni) acc[mi][ni] = (v4f){0.f, 0.f, 0.f, 0.f};

  float4 rb_[2][2];
  // prologue: tile 0
#pragma unroll
  for (int q = 0; q < 2; ++q) {
    rb_[q][0] = ((const float4*)bp[q])[0];
    rb_[q][1] = ((const float4*)bp[q])[1];
  }
#pragma unroll
  for (int q = 0; q < 2; ++q)
    async_lds16(ap[q], &As[0][(w * 2 + q) * 512]);
#pragma unroll
  for (int q = 0; q < 2; ++q)
    st8bf(&Bs[0][(w * 2 + q) * 512 + l * 8], rb_[q][0], rb_[q][1]);

  int pb = 0;
  for (int k0 = 0; k0 < HID; k0 += 32, pb ^= 1) {
    __syncthreads();

    v8s af[4], bf[4];
#pragma unroll
    for (int mi = 0; mi < 4; ++mi)
      af[mi] = *(const v8s*)&As[pb][(wr * 32 + mi * 8) * 64 + lofs];
#pragma unroll
    for (int ni = 0; ni < 4; ++ni)
      bf[ni] = *(const v8s*)&Bs[pb][(wc * 32 + ni * 8) * 64 + lofs];

    int nb = pb ^ 1;
    int kn = k0 + 32;
    if (kn < HID) {
#pragma unroll
      for (int q = 0; q < 2; ++q) {
        rb_[q][0] = ((const float4*)(bp[q] + kn))[0];
        rb_[q][1] = ((const float4*)(bp[q] + kn))[1];
      }
#pragma unroll
      for (int q = 0; q < 2; ++q)
        async_lds16(ap[q] + kn, &As[nb][(w * 2 + q) * 512]);
    }

#pragma unroll
    for (int mi = 0; mi < 4; ++mi)
#pragma unroll
      for (int ni = 0; ni < 4; ++ni)
        acc[mi][ni] = __builtin_amdgcn_mfma_f32_16x16x32_bf16(af[mi], bf[ni], acc[mi][ni], 0, 0, 0);

    if (kn < HID) {
#pragma unroll
      for (int q = 0; q < 2; ++q)
        st8bf(&Bs[nb][(w * 2 + q) * 512 + l * 8], rb_[q][0], rb_[q][1]);
    }
  }

  int col = l & 15, rq = (l >> 4) * 4;
#pragma unroll
  for (int mi = 0; mi < 4; ++mi) {
#pragma unroll
    for (int rr = 0; rr < 4; ++rr) {
      int rl = wr * 64 + mi * 16 + rq + rr;
      if (m0 + rl < cnt) {
        int t = tok[seg0 + m0 + rl];
        float wgt = wl[seg0 + m0 + rl];
        float* ob = out + (size_t)t * DIM + n0 + wc * 64;
#pragma unroll
        for (int ni = 0; ni < 4; ++ni)
          atomicAdd(ob + ni * 16 + col, acc[mi][ni][rr] * wgt);
      }
    }
  }
}

extern "C" void kernel_launch(void* const* d_in, const int* in_sizes, int n_in,
                              void* d_out, int out_size, void* d_ws, size_t ws_size,
                              hipStream_t stream) {
  const float* x   = (const float*)d_in[0];
  const float* rw  = (const float*)d_in[1];
  const float* rb  = (const float*)d_in[2];
  const float* gw  = (const float*)d_in[3];
  const float* uw  = (const float*)d_in[4];
  const float* dw  = (const float*)d_in[5];
  const float* shg = (const float*)d_in[6];
  const float* shu = (const float*)d_in[7];
  const float* shd = (const float*)d_in[8];
  float* out = (float*)d_out;
  char* ws = (char*)d_ws;

  unsigned short* xbf  = (unsigned short*)(ws + OFF_XBF);
  unsigned short* hbuf = (unsigned short*)(ws + OFF_H);
  int*   tok  = (int*)(ws + OFF_TOK);
  float* wl   = (float*)(ws + OFF_WL);
  int*   idxb = (int*)(ws + OFF_IDX);
  float* twb  = (float*)(ws + OFF_TW);
  Stats* st   = (Stats*)(ws + OFF_STATS);

  hipMemsetAsync(d_out, 0, (size_t)out_size * sizeof(float), stream);
  hipMemsetAsync(st, 0, sizeof(Stats), stream);

  router_kernel<<<512, 256, 0, stream>>>(x, rw, rb, xbf, idxb, twb, st);
  scan_kernel<<<1, 64, 0, stream>>>(st, out);
  scatter_kernel<<<8, 256, 0, stream>>>(idxb, twb, st, tok, wl);
  gateup_kernel<<<dim3(16, 16, 9), 256, 0, stream>>>(gw, uw, shg, shu, xbf, tok, st, hbuf);
  down_kernel<<<dim3(8, 16, 9), 256, 0, stream>>>(dw, shd, hbuf, tok, wl, st, out);
}

// Round 4
// 439.884 us; speedup vs baseline: 1.0160x; 1.0160x over previous
//
#include <hip/hip_runtime.h>

#define N_TOK 2048
#define DIM   1024
#define NE    8
#define HID   2048
#define A_SHARED 4096
#define OUT_HID (N_TOK * DIM)

typedef float v4f __attribute__((ext_vector_type(4)));
typedef short v8s __attribute__((ext_vector_type(8)));

// ---- workspace layout (bytes) ----
// No bf16 weight copies: GEMMs read f32 weights directly and convert
// during LDS staging.
#define OFF_XBF   0ull
#define OFF_H     4194304ull
#define OFF_TOK   29360128ull
#define OFF_WL    (OFF_TOK + 24576ull)
#define OFF_IDX   (OFF_WL + 24576ull)
#define OFF_TW    (OFF_IDX + 16384ull)
#define OFF_STATS (OFF_TW + 16384ull)

struct Stats {
  int counts[NE];
  int fill[NE];
  int offs[NE + 2];
  float z2;
  float psum[NE];
};

__device__ __forceinline__ unsigned short f2bf(float f) {
  union { float f; unsigned u; } v; v.f = f;
  unsigned r = v.u + 0x7FFFu + ((v.u >> 16) & 1u);
  return (unsigned short)(r >> 16);
}
__device__ __forceinline__ unsigned pack2bf(float a, float b) {
  return (unsigned)f2bf(a) | ((unsigned)f2bf(b) << 16);
}

// HW packed f32->bf16 (RNE), one instr per 2 values. No builtin on gfx950.
__device__ __forceinline__ unsigned cvt2bf(float a, float b) {
  unsigned r;
  asm("v_cvt_pk_bf16_f32 %0, %1, %2" : "=v"(r) : "v"(a), "v"(b));
  return r;
}
// Convert 8 f32 (two float4) -> 8 bf16, store as one ds_write_b128.
__device__ __forceinline__ void st8bf(unsigned short* p, float4 a, float4 b) {
  uint4 o;
  o.x = cvt2bf(a.x, a.y);
  o.y = cvt2bf(a.z, a.w);
  o.z = cvt2bf(b.x, b.y);
  o.w = cvt2bf(b.z, b.w);
  *(uint4*)p = o;
}

__device__ __forceinline__ void async_lds16(const void* g, void* l) {
  __builtin_amdgcn_global_load_lds(
      (const __attribute__((address_space(1))) void*)g,
      (__attribute__((address_space(3))) void*)l, 16, 0, 0);
}

// ---- router (also emits the bf16 copy of x; x is read here anyway) ----
__global__ __launch_bounds__(256) void router_kernel(
    const float* __restrict__ x, const float* __restrict__ rw, const float* __restrict__ rb,
    unsigned short* __restrict__ xbf,
    int* __restrict__ idxbuf, float* __restrict__ twbuf, Stats* __restrict__ st) {
  int lane = threadIdx.x & 63;
  int wv = threadIdx.x >> 6;
  int n = blockIdx.x * 4 + wv;

  float acc[NE];
#pragma unroll
  for (int e = 0; e < NE; ++e) acc[e] = 0.f;

  const float4* x4 = (const float4*)(x + (size_t)n * DIM);
  uint2* xb2 = (uint2*)xbf + (size_t)n * 256;
#pragma unroll
  for (int q = 0; q < 4; ++q) {
    float4 xv = x4[q * 64 + lane];
    uint2 xo;
    xo.x = pack2bf(xv.x, xv.y);
    xo.y = pack2bf(xv.z, xv.w);
    xb2[q * 64 + lane] = xo;
#pragma unroll
    for (int e = 0; e < NE; ++e) {
      const float4* w4 = (const float4*)(rw + (size_t)e * DIM);
      float4 wvv = w4[q * 64 + lane];
      acc[e] += xv.x * wvv.x + xv.y * wvv.y + xv.z * wvv.z + xv.w * wvv.w;
    }
  }
#pragma unroll
  for (int off = 32; off; off >>= 1) {
#pragma unroll
    for (int e = 0; e < NE; ++e) acc[e] += __shfl_xor(acc[e], off);
  }

  float mx = acc[0];
#pragma unroll
  for (int e = 1; e < NE; ++e) mx = fmaxf(mx, acc[e]);
  float pr[NE];
  float es = 0.f;
#pragma unroll
  for (int e = 0; e < NE; ++e) { pr[e] = __expf(acc[e] - mx); es += pr[e]; }
  float inv = 1.f / es;
#pragma unroll
  for (int e = 0; e < NE; ++e) pr[e] *= inv;
  float z = mx + __logf(es);

  float b0 = -1e30f; int i0 = 0;
#pragma unroll
  for (int e = 0; e < NE; ++e) {
    float bb = acc[e] + rb[e];
    if (bb > b0) { b0 = bb; i0 = e; }
  }
  float b1 = -1e30f; int i1 = 0;
#pragma unroll
  for (int e = 0; e < NE; ++e) {
    if (e == i0) continue;
    float bb = acc[e] + rb[e];
    if (bb > b1) { b1 = bb; i1 = e; }
  }
  float l0 = acc[i0], l1 = acc[i1];
  float m2 = fmaxf(l0, l1);
  float e0 = __expf(l0 - m2), e1 = __expf(l1 - m2);
  float den = 1.f / (e0 + e1);
  float w0 = e0 * den, w1 = e1 * den;

  __shared__ float redp[4][9];
  __shared__ int redc[4][8];
  if (lane == 0) {
    idxbuf[n * 2] = i0; idxbuf[n * 2 + 1] = i1;
    twbuf[n * 2] = w0;  twbuf[n * 2 + 1] = w1;
#pragma unroll
    for (int e = 0; e < NE; ++e) redp[wv][e] = pr[e];
    redp[wv][8] = z * z;
#pragma unroll
    for (int e = 0; e < NE; ++e) redc[wv][e] = (e == i0) + (e == i1);
  }
  __syncthreads();
  int t = threadIdx.x;
  if (t < 9) {
    float s = redp[0][t] + redp[1][t] + redp[2][t] + redp[3][t];
    if (t < 8) atomicAdd(&st->psum[t], s);
    else       atomicAdd(&st->z2, s);
  } else if (t >= 16 && t < 24) {
    int e = t - 16;
    atomicAdd(&st->counts[e], redc[0][e] + redc[1][e] + redc[2][e] + redc[3][e]);
  }
}

// ---- scan ----
__global__ void scan_kernel(Stats* __restrict__ st, float* __restrict__ out) {
  if (threadIdx.x == 0 && blockIdx.x == 0) {
    int o = 0;
#pragma unroll
    for (int e = 0; e < NE; ++e) { st->offs[e] = o; o += st->counts[e]; }
    st->offs[NE] = o;
    st->offs[NE + 1] = o + N_TOK;
    float zl = st->z2 / (float)N_TOK * 1e-4f;
    float lb = 0.f;
#pragma unroll
    for (int e = 0; e < NE; ++e)
      lb += (st->psum[e] / (float)N_TOK) * ((float)st->counts[e] / (float)N_TOK);
    lb *= (float)NE;
    out[OUT_HID + 0] = 0.f;
    out[OUT_HID + 1] = zl;
    out[OUT_HID + 2] = lb;
  }
}

// ---- scatter ----
__global__ __launch_bounds__(256) void scatter_kernel(
    const int* __restrict__ idxbuf, const float* __restrict__ twbuf,
    Stats* __restrict__ st, int* __restrict__ tok, float* __restrict__ wl) {
  int n = blockIdx.x * 256 + threadIdx.x;
#pragma unroll
  for (int k = 0; k < 2; ++k) {
    int e = idxbuf[n * 2 + k];
    int pos = st->offs[e] + atomicAdd(&st->fill[e], 1);
    tok[pos] = n;
    wl[pos] = twbuf[n * 2 + k];
  }
  tok[A_SHARED + n] = n;
  wl[A_SHARED + n] = 1.f;
}

// ============================================================
// LDS swizzle (per Nx32 bf16 tile): super-rows of 128 B (8
// granules of 16 B); granule g of super-row R holds chunk
// g^(R&7). Fragment ds_read_b128s hit all 8 bank-groups, 2
// lanes each (free). Slab = 16 rows = 8 super-rows; fragment
// base super-rows stay multiples of 8, so swizzle consistency
// is preserved for M=64 (bases {0,8,16,24}).
//
// r3 -> r4: GEMMs were latency-bound (down: occ 12.8%, Mfma 8%,
// HBM 16%). Fix = parallelism, not bytes: M-tile 64 (half acc,
// 24/40 KB LDS -> 4-6 resident blocks/CU) and split-K x2 for
// down (K=2048 -> 2x1024, atomicAdd output). Active blocks:
// 384 -> 1536 (down), 768 -> 1536 (gateup).
// ============================================================

// ---- gate+up grouped GEMM, 64x128 tile, double-buffered ----
__global__ __launch_bounds__(256, 2) void gateup_kernel(
    const float* __restrict__ gw, const float* __restrict__ uw,
    const float* __restrict__ shg, const float* __restrict__ shu,
    const unsigned short* __restrict__ xbf, const int* __restrict__ tok,
    const Stats* __restrict__ st, unsigned short* __restrict__ hbuf) {
  int e = blockIdx.z;
  int seg0 = st->offs[e];
  int cnt = st->offs[e + 1] - seg0;
  int m0 = blockIdx.y * 64;           // m-tile on Y (sparse)
  if (m0 >= cnt) return;
  int n0 = blockIdx.x * 128;          // n-tile on X (dense)

  __shared__ alignas(16) unsigned short As[2][64 * 32];
  __shared__ alignas(16) unsigned short Bg[2][128 * 32];
  __shared__ alignas(16) unsigned short Bu[2][128 * 32];

  int tid = threadIdx.x, l = tid & 63, w = tid >> 6;
  int wr = w >> 1, wc = w & 1;

  int sj = l >> 3;
  int ss = (l & 7) ^ sj;
  int grow = 2 * sj + (ss >> 2);
  int gch = ss & 3;

  const float* gbase = (e < NE) ? gw + (size_t)e * HID * DIM : shg;
  const float* ubase = (e < NE) ? uw + (size_t)e * HID * DIM : shu;

  // A: one 16-row slab per wave (64 rows total)
  int arow = w * 16 + grow;
  int ar = m0 + arow; if (ar > cnt - 1) ar = cnt - 1;
  const unsigned short* ap = xbf + (size_t)tok[seg0 + ar] * DIM + gch * 8;

  // B: two 16-row slabs per wave (128 rows total)
  const float* gp[2];
  const float* up[2];
#pragma unroll
  for (int q = 0; q < 2; ++q) {
    int row = (w * 2 + q) * 16 + grow;
    size_t wb = (size_t)(n0 + row) * DIM + gch * 8;
    gp[q] = gbase + wb;
    up[q] = ubase + wb;
  }

  int lh = (l & 15) >> 1;
  int lofs = lh * 64 + ((((l & 1) * 4 + (l >> 4)) ^ lh) * 8);

  v4f accg[2][4], accu[2][4];
#pragma unroll
  for (int mi = 0; mi < 2; ++mi)
#pragma unroll
    for (int ni = 0; ni < 4; ++ni) {
      accg[mi][ni] = (v4f){0.f, 0.f, 0.f, 0.f};
      accu[mi][ni] = (v4f){0.f, 0.f, 0.f, 0.f};
    }

  float4 rg[2][2], ru[2][2];
  // prologue: tile 0 — B via regs, A via async
#pragma unroll
  for (int q = 0; q < 2; ++q) {
    rg[q][0] = ((const float4*)gp[q])[0];
    rg[q][1] = ((const float4*)gp[q])[1];
    ru[q][0] = ((const float4*)up[q])[0];
    ru[q][1] = ((const float4*)up[q])[1];
  }
  async_lds16(ap, &As[0][w * 512]);
#pragma unroll
  for (int q = 0; q < 2; ++q) {
    st8bf(&Bg[0][(w * 2 + q) * 512 + l * 8], rg[q][0], rg[q][1]);
    st8bf(&Bu[0][(w * 2 + q) * 512 + l * 8], ru[q][0], ru[q][1]);
  }

  int pb = 0;
  for (int k0 = 0; k0 < DIM; k0 += 32, pb ^= 1) {
    __syncthreads();

    v8s af[2], bgf[4], buf_[4];
#pragma unroll
    for (int mi = 0; mi < 2; ++mi)
      af[mi] = *(const v8s*)&As[pb][(wr * 16 + mi * 8) * 64 + lofs];
#pragma unroll
    for (int ni = 0; ni < 4; ++ni) {
      bgf[ni]  = *(const v8s*)&Bg[pb][(wc * 32 + ni * 8) * 64 + lofs];
      buf_[ni] = *(const v8s*)&Bu[pb][(wc * 32 + ni * 8) * 64 + lofs];
    }

    int nb = pb ^ 1;
    int kn = k0 + 32;
    if (kn < DIM) {
#pragma unroll
      for (int q = 0; q < 2; ++q) {
        rg[q][0] = ((const float4*)(gp[q] + kn))[0];
        rg[q][1] = ((const float4*)(gp[q] + kn))[1];
        ru[q][0] = ((const float4*)(up[q] + kn))[0];
        ru[q][1] = ((const float4*)(up[q] + kn))[1];
      }
      async_lds16(ap + kn, &As[nb][w * 512]);
    }

#pragma unroll
    for (int mi = 0; mi < 2; ++mi)
#pragma unroll
      for (int ni = 0; ni < 4; ++ni) {
        accg[mi][ni] = __builtin_amdgcn_mfma_f32_16x16x32_bf16(af[mi], bgf[ni], accg[mi][ni], 0, 0, 0);
        accu[mi][ni] = __builtin_amdgcn_mfma_f32_16x16x32_bf16(af[mi], buf_[ni], accu[mi][ni], 0, 0, 0);
      }

    if (kn < DIM) {
#pragma unroll
      for (int q = 0; q < 2; ++q) {
        st8bf(&Bg[nb][(w * 2 + q) * 512 + l * 8], rg[q][0], rg[q][1]);
        st8bf(&Bu[nb][(w * 2 + q) * 512 + l * 8], ru[q][0], ru[q][1]);
      }
    }
  }

  int col = l & 15, rq = (l >> 4) * 4;
#pragma unroll
  for (int mi = 0; mi < 2; ++mi) {
#pragma unroll
    for (int rr = 0; rr < 4; ++rr) {
      int rl = wr * 32 + mi * 16 + rq + rr;
      if (m0 + rl < cnt) {
        size_t rowb = (size_t)(seg0 + m0 + rl) * HID + n0 + wc * 64;
#pragma unroll
        for (int ni = 0; ni < 4; ++ni) {
          float g = accg[mi][ni][rr], u = accu[mi][ni][rr];
          hbuf[rowb + ni * 16 + col] = f2bf(g * u / (1.f + __expf(-g)));
        }
      }
    }
  }
}

// ---- down grouped GEMM, 64x128 tile, split-K x2, double-buffered ----
#define KSPL (HID / 2)
__global__ __launch_bounds__(256, 2) void down_kernel(
    const float* __restrict__ dw, const float* __restrict__ shd,
    const unsigned short* __restrict__ hbuf,
    const int* __restrict__ tok, const float* __restrict__ wl,
    const Stats* __restrict__ st, float* __restrict__ out) {
  int zz = blockIdx.z;
  int e = zz >> 1;
  int kb = (zz & 1) * KSPL;           // K half
  int seg0 = st->offs[e];
  int cnt = st->offs[e + 1] - seg0;
  int m0 = blockIdx.y * 64;           // m-tile on Y (sparse)
  if (m0 >= cnt) return;
  int n0 = blockIdx.x * 128;          // n-tile on X (dense, over DIM)

  __shared__ alignas(16) unsigned short As[2][64 * 32];
  __shared__ alignas(16) unsigned short Bs[2][128 * 32];

  int tid = threadIdx.x, l = tid & 63, w = tid >> 6;
  int wr = w >> 1, wc = w & 1;

  int sj = l >> 3;
  int ss = (l & 7) ^ sj;
  int grow = 2 * sj + (ss >> 2);
  int gch = ss & 3;

  const float* dbase = (e < NE) ? dw + (size_t)e * DIM * HID : shd;

  // A: one 16-row slab per wave (64 rows total)
  int arow = w * 16 + grow;
  int ar = m0 + arow; if (ar > cnt - 1) ar = cnt - 1;
  const unsigned short* ap = hbuf + (size_t)(seg0 + ar) * HID + gch * 8 + kb;

  // B: two 16-row slabs per wave (128 rows total)
  const float* bp[2];
#pragma unroll
  for (int q = 0; q < 2; ++q) {
    int row = (w * 2 + q) * 16 + grow;
    bp[q] = dbase + (size_t)(n0 + row) * HID + gch * 8 + kb;
  }

  int lh = (l & 15) >> 1;
  int lofs = lh * 64 + ((((l & 1) * 4 + (l >> 4)) ^ lh) * 8);

  v4f acc[2][4];
#pragma unroll
  for (int mi = 0; mi < 2; ++mi)
#pragma unroll
    for (int ni = 0; ni < 4; ++ni) acc[mi][ni] = (v4f){0.f, 0.f, 0.f, 0.f};

  float4 rb_[2][2];
  // prologue: tile 0
#pragma unroll
  for (int q = 0; q < 2; ++q) {
    rb_[q][0] = ((const float4*)bp[q])[0];
    rb_[q][1] = ((const float4*)bp[q])[1];
  }
  async_lds16(ap, &As[0][w * 512]);
#pragma unroll
  for (int q = 0; q < 2; ++q)
    st8bf(&Bs[0][(w * 2 + q) * 512 + l * 8], rb_[q][0], rb_[q][1]);

  int pb = 0;
  for (int k0 = 0; k0 < KSPL; k0 += 32, pb ^= 1) {
    __syncthreads();

    v8s af[2], bf[4];
#pragma unroll
    for (int mi = 0; mi < 2; ++mi)
      af[mi] = *(const v8s*)&As[pb][(wr * 16 + mi * 8) * 64 + lofs];
#pragma unroll
    for (int ni = 0; ni < 4; ++ni)
      bf[ni] = *(const v8s*)&Bs[pb][(wc * 32 + ni * 8) * 64 + lofs];

    int nb = pb ^ 1;
    int kn = k0 + 32;
    if (kn < KSPL) {
#pragma unroll
      for (int q = 0; q < 2; ++q) {
        rb_[q][0] = ((const float4*)(bp[q] + kn))[0];
        rb_[q][1] = ((const float4*)(bp[q] + kn))[1];
      }
      async_lds16(ap + kn, &As[nb][w * 512]);
    }

#pragma unroll
    for (int mi = 0; mi < 2; ++mi)
#pragma unroll
      for (int ni = 0; ni < 4; ++ni)
        acc[mi][ni] = __builtin_amdgcn_mfma_f32_16x16x32_bf16(af[mi], bf[ni], acc[mi][ni], 0, 0, 0);

    if (kn < KSPL) {
#pragma unroll
      for (int q = 0; q < 2; ++q)
        st8bf(&Bs[nb][(w * 2 + q) * 512 + l * 8], rb_[q][0], rb_[q][1]);
    }
  }

  int col = l & 15, rq = (l >> 4) * 4;
#pragma unroll
  for (int mi = 0; mi < 2; ++mi) {
#pragma unroll
    for (int rr = 0; rr < 4; ++rr) {
      int rl = wr * 32 + mi * 16 + rq + rr;
      if (m0 + rl < cnt) {
        int t = tok[seg0 + m0 + rl];
        float wgt = wl[seg0 + m0 + rl];
        float* ob = out + (size_t)t * DIM + n0 + wc * 64;
#pragma unroll
        for (int ni = 0; ni < 4; ++ni)
          atomicAdd(ob + ni * 16 + col, acc[mi][ni][rr] * wgt);
      }
    }
  }
}

extern "C" void kernel_launch(void* const* d_in, const int* in_sizes, int n_in,
                              void* d_out, int out_size, void* d_ws, size_t ws_size,
                              hipStream_t stream) {
  const float* x   = (const float*)d_in[0];
  const float* rw  = (const float*)d_in[1];
  const float* rb  = (const float*)d_in[2];
  const float* gw  = (const float*)d_in[3];
  const float* uw  = (const float*)d_in[4];
  const float* dw  = (const float*)d_in[5];
  const float* shg = (const float*)d_in[6];
  const float* shu = (const float*)d_in[7];
  const float* shd = (const float*)d_in[8];
  float* out = (float*)d_out;
  char* ws = (char*)d_ws;

  unsigned short* xbf  = (unsigned short*)(ws + OFF_XBF);
  unsigned short* hbuf = (unsigned short*)(ws + OFF_H);
  int*   tok  = (int*)(ws + OFF_TOK);
  float* wl   = (float*)(ws + OFF_WL);
  int*   idxb = (int*)(ws + OFF_IDX);
  float* twb  = (float*)(ws + OFF_TW);
  Stats* st   = (Stats*)(ws + OFF_STATS);

  hipMemsetAsync(d_out, 0, (size_t)out_size * sizeof(float), stream);
  hipMemsetAsync(st, 0, sizeof(Stats), stream);

  router_kernel<<<512, 256, 0, stream>>>(x, rw, rb, xbf, idxb, twb, st);
  scan_kernel<<<1, 64, 0, stream>>>(st, out);
  scatter_kernel<<<8, 256, 0, stream>>>(idxb, twb, st, tok, wl);
  gateup_kernel<<<dim3(16, 32, 9), 256, 0, stream>>>(gw, uw, shg, shu, xbf, tok, st, hbuf);
  down_kernel<<<dim3(8, 32, 18), 256, 0, stream>>>(dw, shd, hbuf, tok, wl, st, out);
}